// Round 1
// baseline (209.013 us; speedup 1.0000x reference)
//
#include <hip/hip_runtime.h>

#define SDIM 14
#define L_COORD 5.0f
#define L_NOOBJ 0.5f
#define BATCH 4096
#define CELLS (BATCH * SDIM * SDIM)   // 802816
#define BLOCK 256
#define NBLOCKS (CELLS / BLOCK)       // 3136
#define CELL_F 30

// Direct-load version: no LDS staging. Each thread owns one cell and reads
// its 30+30 floats as float2 (cell stride 120 B is 8-B aligned). A wave's
// 30 load instructions re-touch the same ~240 cache lines -> L1-amortized.
// __launch_bounds__(256,4): cap VGPR at 128 -> 4 waves/SIMD = 16 waves/CU
// (vs 2 blocks/CU = 8 waves/CU when the 60 KB LDS staging capped residency).
__global__ __launch_bounds__(BLOCK, 4) void yolo_partial(
    const float* __restrict__ pred, const float* __restrict__ targ,
    float* __restrict__ partial) {
    const int cell = blockIdx.x * BLOCK + threadIdx.x;
    const float* P = pred + (size_t)cell * CELL_F;
    const float* T = targ + (size_t)cell * CELL_F;

    // ---- box region: channels 0..9 of both tensors (5 float2 each) ----
    float Pb[10], Tb[10];
#pragma unroll
    for (int j = 0; j < 5; ++j) {
        const float2 a = *reinterpret_cast<const float2*>(P + 2 * j);
        const float2 b = *reinterpret_cast<const float2*>(T + 2 * j);
        Pb[2 * j] = a.x; Pb[2 * j + 1] = a.y;
        Tb[2 * j] = b.x; Tb[2 * j + 1] = b.y;
    }

    // ---- class loss: channels 10..29, streamed as float2 pairs ----
    float cls = 0.0f;
#pragma unroll
    for (int j = 5; j < 15; ++j) {
        const float2 a = *reinterpret_cast<const float2*>(P + 2 * j);
        const float2 b = *reinterpret_cast<const float2*>(T + 2 * j);
        const float dx = a.x - b.x;
        const float dy = a.y - b.y;
        cls += dx * dx;   // keep per-channel accumulation order identical
        cls += dy * dy;   // to the previous (verified absmax=0) kernel
    }

    // ---- branchless per-cell loss (identical arithmetic to old branch) ----
    const float d4 = Pb[4] - Tb[4];
    const float d9 = Pb[9] - Tb[9];
    const float noobj_l = L_NOOBJ * (d4 * d4 + d9 * d9);

    const float invS = 1.0f / (float)SDIM;
    const float t1x = Tb[0] * invS - Tb[2] * 0.5f;
    const float t1y = Tb[1] * invS - Tb[3] * 0.5f;
    const float t2x = Tb[0] * invS + Tb[2] * 0.5f;
    const float t2y = Tb[1] * invS + Tb[3] * 0.5f;
    const float area_t = (t2x - t1x) * (t2y - t1y);

    float iou0 = 0.0f, iou1 = 0.0f;
#pragma unroll
    for (int k = 0; k < 2; ++k) {
        const float bx = Pb[5 * k + 0], by = Pb[5 * k + 1];
        const float bw = Pb[5 * k + 2], bh = Pb[5 * k + 3];
        const float p1x = bx * invS - bw * 0.5f;
        const float p1y = by * invS - bh * 0.5f;
        const float p2x = bx * invS + bw * 0.5f;
        const float p2y = by * invS + bh * 0.5f;
        const float ltx = fmaxf(p1x, t1x), lty = fmaxf(p1y, t1y);
        const float rbx = fminf(p2x, t2x), rby = fminf(p2y, t2y);
        const float wx = fmaxf(rbx - ltx, 0.0f);
        const float wy = fmaxf(rby - lty, 0.0f);
        const float inter = wx * wy;
        const float area_p = (p2x - p1x) * (p2y - p1y);
        const float v = inter / (area_p + area_t - inter);
        if (k == 0) iou0 = v; else iou1 = v;
    }

    const bool pick1 = (iou0 <= iou1);
    const float iou_best = pick1 ? iou1 : iou0;
    const float psx = pick1 ? Pb[5] : Pb[0];
    const float psy = pick1 ? Pb[6] : Pb[1];
    const float psw = pick1 ? Pb[7] : Pb[2];
    const float psh = pick1 ? Pb[8] : Pb[3];
    const float psc = pick1 ? Pb[9] : Pb[4];
    const float tsx = pick1 ? Tb[5] : Tb[0];
    const float tsy = pick1 ? Tb[6] : Tb[1];
    const float tsw = pick1 ? Tb[7] : Tb[2];
    const float tsh = pick1 ? Tb[8] : Tb[3];

    const float dx = psx - tsx, dy = psy - tsy;
    const float dw = sqrtf(psw) - sqrtf(tsw);   // inputs in [0.01,1]: safe
    const float dh = sqrtf(psh) - sqrtf(tsh);
    const float reg = dx * dx + dy * dy + dw * dw + dh * dh;
    const float dconf = psc - iou_best;
    const float obj_l = cls + L_COORD * reg + dconf * dconf;

    float loss = (Tb[4] > 0.0f) ? obj_l : noobj_l;

    // ---- wave (64-lane) shuffle reduction, same order as before ----
#pragma unroll
    for (int off = 32; off > 0; off >>= 1)
        loss += __shfl_down(loss, off, 64);

    __shared__ float wsum[BLOCK / 64];
    const int lane = threadIdx.x & 63;
    const int wave = threadIdx.x >> 6;
    if (lane == 0) wsum[wave] = loss;
    __syncthreads();
    if (threadIdx.x == 0)
        partial[blockIdx.x] = wsum[0] + wsum[1] + wsum[2] + wsum[3];
}

__global__ __launch_bounds__(BLOCK) void yolo_final(
    const float* __restrict__ partial, float* __restrict__ out) {
    float s = 0.0f;
    for (int i = threadIdx.x; i < NBLOCKS; i += BLOCK) s += partial[i];
#pragma unroll
    for (int off = 32; off > 0; off >>= 1)
        s += __shfl_down(s, off, 64);
    __shared__ float wsum[BLOCK / 64];
    const int lane = threadIdx.x & 63;
    const int wave = threadIdx.x >> 6;
    if (lane == 0) wsum[wave] = s;
    __syncthreads();
    if (threadIdx.x == 0)
        out[0] = (wsum[0] + wsum[1] + wsum[2] + wsum[3]) * (1.0f / (float)BATCH);
}

extern "C" void kernel_launch(void* const* d_in, const int* in_sizes, int n_in,
                              void* d_out, int out_size, void* d_ws, size_t ws_size,
                              hipStream_t stream) {
    const float* pred = (const float*)d_in[0];
    const float* targ = (const float*)d_in[1];
    float* out = (float*)d_out;
    float* partial = (float*)d_ws;   // NBLOCKS floats = 12.5 KB scratch

    yolo_partial<<<NBLOCKS, BLOCK, 0, stream>>>(pred, targ, partial);
    yolo_final<<<1, BLOCK, 0, stream>>>(partial, out);
}